// Round 2
// baseline (774.138 us; speedup 1.0000x reference)
//
#include <hip/hip_runtime.h>
#include <cstddef>

#define NB 4096
#define NT 64
#define NOBS 64
#define NH 64
#define NA 8
#define NS 201

// d_out layout (floats):
//   logits [B,T,A]  @ 0          (2097152)
//   values [T*B]    @ 2097152    (262144)
//   stack  [B,S,H]  @ 2359296    (52690944)
//   ptrs   [B]      @ 55050240   (4096, stored as float)

__global__ void copy_stack_kernel(const float4* __restrict__ src,
                                  float4* __restrict__ dst, int n4) {
    int i = blockIdx.x * blockDim.x + threadIdx.x;
    int stride = gridDim.x * blockDim.x;
    for (; i < n4; i += stride) dst[i] = src[i];
}

__launch_bounds__(256, 2)
__global__ void stacknet_kernel(const float* __restrict__ x,
                                const int* __restrict__ ptrs_in,
                                const float* __restrict__ W1,
                                const float* __restrict__ b1,
                                const float* __restrict__ W2,
                                const float* __restrict__ b2,
                                const float* __restrict__ Ws,
                                const float* __restrict__ bs,
                                const float* __restrict__ Wp,
                                const float* __restrict__ bp,
                                const float* __restrict__ Wv,
                                const float* __restrict__ bv,
                                float* __restrict__ logits_out,
                                float* __restrict__ values_out,
                                float* __restrict__ stack,
                                float* __restrict__ ptrs_out) {
    const int lane = threadIdx.x & 63;
    const int wv = threadIdx.x >> 6;
    const int b = (blockIdx.x << 2) + wv;
    const int aa = lane & 15;            // head index (0..11 valid, padded to 16)

    // Transposed head weights: shwT[k][a] = W_head[a][k], padded to 16 heads.
    __shared__ float shwT[64 * 16];
    __shared__ float shb[16];
    __shared__ float vbuf[4][192];       // per-wave: [0..63]=x_t|top? no: [0..63]=x, [64..127]=top, [128..191]=h
    __shared__ float pbuf[4][64];        // per-wave p vector for head dots

    for (int i = threadIdx.x; i < 64 * 16; i += 256) {
        int k = i >> 4, a = i & 15;
        float w = 0.0f;
        if (a < 3)       w = Ws[a * 64 + k];
        else if (a < 11) w = Wp[(a - 3) * 64 + k];
        else if (a == 11) w = Wv[k];
        shwT[i] = w;
    }
    if (threadIdx.x < 16) {
        int a = threadIdx.x;
        float bb = 0.0f;
        if (a < 3) bb = bs[a];
        else if (a < 11) bb = bp[a - 3];
        else if (a == 11) bb = bv[0];
        shb[a] = bb;
    }
    __syncthreads();

    // W1 row `lane` (128 floats) and W2 row `lane` (64 floats) in registers.
    float w1r[128];
#pragma unroll
    for (int j = 0; j < 32; ++j) {
        float4 tW = ((const float4*)W1)[lane * 32 + j];
        w1r[4*j] = tW.x; w1r[4*j+1] = tW.y; w1r[4*j+2] = tW.z; w1r[4*j+3] = tW.w;
    }
    float w2r[64];
#pragma unroll
    for (int j = 0; j < 16; ++j) {
        float4 tW = ((const float4*)W2)[lane * 16 + j];
        w2r[4*j] = tW.x; w2r[4*j+1] = tW.y; w2r[4*j+2] = tW.z; w2r[4*j+3] = tW.w;
    }
    float b1r = b1[lane];
    float b2r = b2[lane];

    int ptr = ptrs_in[b];
    const float* xb  = x + (size_t)b * NT * NOBS;
    float* stk       = stack + (size_t)b * NS * NH;
    float* lgb       = logits_out + (size_t)b * NT * NA;

    for (int t = 0; t < NT; ++t) {
        float xv = xb[t * 64 + lane];
        float tv = stk[ptr * 64 + lane];      // top = stack[b, ptr]
        vbuf[wv][lane]      = xv;
        vbuf[wv][64 + lane] = tv;

        // h = tanh( (concat(x_t, top) @ W1.T) + b1 )
        // BLAS order: single FMA chain, k ascending, bias added AFTER the dot.
        float acc = 0.0f;
        const float4* vb4 = (const float4*)(&vbuf[wv][0]);
#pragma unroll
        for (int j = 0; j < 32; ++j) {
            float4 v = vb4[j];                 // same-addr broadcast read
            acc = fmaf(w1r[4*j],   v.x, acc);
            acc = fmaf(w1r[4*j+1], v.y, acc);
            acc = fmaf(w1r[4*j+2], v.z, acc);
            acc = fmaf(w1r[4*j+3], v.w, acc);
        }
        float h = tanhf(acc + b1r);
        vbuf[wv][128 + lane] = h;

        // p = tanh( (h @ W2.T) + b2 )
        float acc2 = 0.0f;
        const float4* hb4 = (const float4*)(&vbuf[wv][128]);
#pragma unroll
        for (int j = 0; j < 16; ++j) {
            float4 v = hb4[j];
            acc2 = fmaf(w2r[4*j],   v.x, acc2);
            acc2 = fmaf(w2r[4*j+1], v.y, acc2);
            acc2 = fmaf(w2r[4*j+2], v.z, acc2);
            acc2 = fmaf(w2r[4*j+3], v.w, acc2);
        }
        float p = tanhf(acc2 + b2r);
        pbuf[wv][lane] = p;

        // 12 head dots as sequential-k FMA chains (BLAS order), lane a = head a.
        float hacc = 0.0f;
#pragma unroll
        for (int k = 0; k < 64; ++k) {
            hacc = fmaf(pbuf[wv][k], shwT[k * 16 + aa], hacc);
        }
        float sv = hacc + shb[aa];

        // Broadcast decision scores to all lanes (wave-uniform decision).
        float s0 = __shfl(sv, 0, 64);
        float s1 = __shfl(sv, 1, 64);
        float s2 = __shfl(sv, 2, 64);

        // Mimic softmax -> argmax (first strict max), including exp and divide
        // rounding, to match the reference's tie behavior.
        float m = fmaxf(fmaxf(s0, s1), s2);
        float e0 = expf(s0 - m);
        float e1 = expf(s1 - m);
        float e2 = expf(s2 - m);
        float S = (e0 + e1) + e2;
        float p0 = e0 / S, p1 = e1 / S, p2 = e2 / S;
        int op = 0;
        float pm = p0;
        if (p1 > pm) { pm = p1; op = 1; }
        if (p2 > pm) { op = 2; }

        if (op == 2) stk[ptr * 64 + lane] = p;   // push overwrites top slot
        ptr = ptr + op - 1;
        if (ptr < 0) ptr = 0;

        // Outputs: lanes 3..10 hold the 8 policy logits, lane 11 the value.
        if (lane >= 3 && lane <= 10) {
            lgb[t * NA + (lane - 3)] = sv;
        }
        if (lane == 11) {
            values_out[(size_t)t * NB + b] = sv;   // time-major [T*B]
        }
    }
    if (lane == 0) ptrs_out[b] = (float)ptr;
}

extern "C" void kernel_launch(void* const* d_in, const int* in_sizes, int n_in,
                              void* d_out, int out_size, void* d_ws, size_t ws_size,
                              hipStream_t stream) {
    const float* x        = (const float*)d_in[0];
    const float* stack_in = (const float*)d_in[1];
    const int*   ptrs_in  = (const int*)d_in[2];
    const float* W1 = (const float*)d_in[3];
    const float* b1 = (const float*)d_in[4];
    const float* W2 = (const float*)d_in[5];
    const float* b2 = (const float*)d_in[6];
    const float* Ws = (const float*)d_in[7];
    const float* bs = (const float*)d_in[8];
    const float* Wp = (const float*)d_in[9];
    const float* bp = (const float*)d_in[10];
    const float* Wv = (const float*)d_in[11];
    const float* bv = (const float*)d_in[12];

    float* out      = (float*)d_out;
    float* logits   = out;                 // 2097152
    float* values   = out + 2097152;       // 262144
    float* stack    = out + 2359296;       // 52690944
    float* ptrs_out = out + 55050240;      // 4096

    int n4 = 52690944 / 4;
    copy_stack_kernel<<<4096, 256, 0, stream>>>((const float4*)stack_in,
                                                (float4*)stack, n4);
    stacknet_kernel<<<1024, 256, 0, stream>>>(x, ptrs_in, W1, b1, W2, b2,
                                              Ws, bs, Wp, bp, Wv, bv,
                                              logits, values, stack, ptrs_out);
}